// Round 2
// baseline (1275.902 us; speedup 1.0000x reference)
//
#include <hip/hip_runtime.h>
#include <hip/hip_bf16.h>
#include <math.h>

// Problem constants: B=4, L=1024, D=512, H=8, C=8, Dk=64
#define NB 4
#define NL 1024
#define ND 512
#define NH 8
#define NC 8
#define NDK 64

static constexpr float KL3_CONST = 115.36544595161891f; // -0.5*(1+ln0.01)*64, per clustering call

typedef __bf16 bf16x8 __attribute__((ext_vector_type(8)));
typedef float  f32x4v __attribute__((ext_vector_type(4)));
typedef unsigned short u16x4 __attribute__((ext_vector_type(4)));

__device__ __forceinline__ unsigned short bf16u(float f) {
    return __builtin_bit_cast(unsigned short, (__bf16)f);
}

// ---------------------------------------------------------------------------
// Clustering: probs (softmax over C of gaussian log-pdf), kl partials, div
// diag partials, and Gram matrix G = P^T P (C x C) per (b,h,side).
// grid: (L/256, B*H, 2)  block: 256
// ---------------------------------------------------------------------------
__global__ __launch_bounds__(256) void cluster_kernel(
    const float* __restrict__ query, const float* __restrict__ key,
    const float* __restrict__ tok_mu, const float* __restrict__ tok_log_var,
    const float* __restrict__ tok_log_prior,
    float* __restrict__ probs_q, float* __restrict__ probs_k,
    float* __restrict__ acc_kl, float* __restrict__ acc_div,
    float* __restrict__ Gacc)
{
    const int tid  = threadIdx.x;
    const int bh   = blockIdx.y;
    const int b    = bh >> 3, h = bh & 7;
    const int side = blockIdx.z;
    const float* src = side ? key : query;
    float* probs_out = side ? probs_k : probs_q;

    __shared__ alignas(16) float mu_s[512];
    __shared__ alignas(16) float iv_s[512];
    __shared__ float lvsum_s[8], alpha_s[8], logp_s[8], prior_s[8];
    __shared__ float Pl[256 * 9];     // probs per-thread, stride 9 (bank-spread)
    __shared__ float Gpart[4][64];
    __shared__ float red_s[8];

    for (int i = tid; i < 512; i += 256) {
        mu_s[i] = tok_mu[h * 512 + i];
        float lv = tok_log_var[h * 512 + i];
        iv_s[i] = __expf(-lv);
    }
    if (tid < 8) {
        float ls = 0.f, al = 0.f;
        for (int d = 0; d < 64; ++d) {
            float lv = tok_log_var[(h * 8 + tid) * 64 + d];
            ls += lv;
            al += 0.01f * __expf(-lv) + lv;   // avar/var + lv, avar = exp(ln .01)
        }
        lvsum_s[tid] = ls; alpha_s[tid] = al;
    }
    if (tid == 0) {
        float lp[8]; float mx = -1e30f;
        for (int c = 0; c < 8; ++c) { lp[c] = tok_log_prior[h * 8 + c]; mx = fmaxf(mx, lp[c]); }
        float se = 0.f;
        for (int c = 0; c < 8; ++c) se += __expf(lp[c] - mx);
        float lse = mx + __logf(se);
        for (int c = 0; c < 8; ++c) { logp_s[c] = lp[c] - lse; prior_s[c] = __expf(lp[c] - lse); }
    }
    __syncthreads();

    const int l = blockIdx.x * 256 + tid;
    const float4* xp = (const float4*)(src + ((size_t)(b * NL + l)) * ND + h * NDK);
    float4 xr[16];
#pragma unroll
    for (int i = 0; i < 16; ++i) xr[i] = xp[i];

    float ms[8];
#pragma unroll
    for (int c = 0; c < 8; ++c) {
        const float4* mc = (const float4*)(mu_s + c * 64);
        const float4* ic = (const float4*)(iv_s + c * 64);
        float s = 0.f;
#pragma unroll
        for (int i = 0; i < 16; ++i) {
            float4 m4 = mc[i], v4 = ic[i], x4 = xr[i];
            float dx = x4.x - m4.x; s = fmaf(dx * dx, v4.x, s);
            float dy = x4.y - m4.y; s = fmaf(dy * dy, v4.y, s);
            float dz = x4.z - m4.z; s = fmaf(dz * dz, v4.z, s);
            float dw = x4.w - m4.w; s = fmaf(dw * dw, v4.w, s);
        }
        ms[c] = s;
    }

    float lpdf[8]; float mx = -1e30f;
#pragma unroll
    for (int c = 0; c < 8; ++c) {
        lpdf[c] = -0.5f * (ms[c] + lvsum_s[c]) + logp_s[c];
        mx = fmaxf(mx, lpdf[c]);
    }
    float e[8]; float se = 0.f;
#pragma unroll
    for (int c = 0; c < 8; ++c) { e[c] = __expf(lpdf[c] - mx); se += e[c]; }
    float lse = __logf(se);
    float inv = 1.f / se;
    float p[8]; float kl1 = 0.f, kl2 = 0.f, sqq = 0.f;
#pragma unroll
    for (int c = 0; c < 8; ++c) {
        p[c] = e[c] * inv;
        float logprob = lpdf[c] - mx - lse;
        kl1 += prior_s[c] * (logp_s[c] - logprob);
        kl2 += p[c] * (ms[c] + alpha_s[c]);
        sqq = fmaf(p[c], p[c], sqq);
    }

    float* po = probs_out + ((size_t)((b * NH + h) * NL + l)) * NC;
    ((float4*)po)[0] = make_float4(p[0], p[1], p[2], p[3]);
    ((float4*)po)[1] = make_float4(p[4], p[5], p[6], p[7]);
#pragma unroll
    for (int c = 0; c < 8; ++c) Pl[tid * 9 + c] = p[c];

    float dterm = 1.25f * (sqq - 1.f) * (sqq - 1.f) - 0.75f * sqq * sqq;
    float klv = kl1 + 0.5f * kl2;
    __syncthreads();

    // Gram partials: thread (qt,pos) sums P[l][c1]*P[l][c2] over its quarter
    {
        int qt = tid >> 6, pos = tid & 63, c1 = pos >> 3, c2 = pos & 7;
        float g = 0.f;
        for (int i = 0; i < 64; ++i) {
            int ll = qt * 64 + i;
            g = fmaf(Pl[ll * 9 + c1], Pl[ll * 9 + c2], g);
        }
        Gpart[qt][pos] = g;
    }

    // block reduce kl and div-diag partials
#pragma unroll
    for (int o = 32; o > 0; o >>= 1) {
        klv   += __shfl_down(klv, o);
        dterm += __shfl_down(dterm, o);
    }
    if ((tid & 63) == 0) { red_s[tid >> 6] = klv; red_s[4 + (tid >> 6)] = dterm; }
    __syncthreads();
    if (tid == 0) {
        atomicAdd(acc_kl + b,  red_s[0] + red_s[1] + red_s[2] + red_s[3]);
        atomicAdd(acc_div + b, red_s[4] + red_s[5] + red_s[6] + red_s[7]);
    }
    if (tid < 64) {
        float g = Gpart[0][tid] + Gpart[1][tid] + Gpart[2][tid] + Gpart[3][tid];
        atomicAdd(Gacc + ((size_t)((side * NB + b) * NH + h)) * 64 + tid, g);
    }
}

// ---------------------------------------------------------------------------
// bf16 MFMA GEMM: out = (A @ W^T + bias) * scale.  A:[M,512] W:[512,512] row=N
// 128x128 tile, BK=32, 4 waves (2x2), each wave 4x4 of 16x16x32 MFMA tiles.
// fp32 inputs converted to bf16 during LDS staging. grid: (4, M/128, nbatch)
// ---------------------------------------------------------------------------
struct GemmArgs { const float* A; const float* W; const float* bias; float* out; float scale; };

__global__ __launch_bounds__(256) void gemm_bt(GemmArgs g0, GemmArgs g1, GemmArgs g2)
{
    GemmArgs g = (blockIdx.z == 0) ? g0 : ((blockIdx.z == 1) ? g1 : g2);
    const int tid = threadIdx.x;
    const int n0 = blockIdx.x * 128, m0 = blockIdx.y * 128;

    __shared__ alignas(16) unsigned short As[128 * 40];  // stride 40 to break conflicts
    __shared__ alignas(16) unsigned short Ws[128 * 40];

    const int kc = tid & 7;     // k-chunk (float4) 0..7
    const int r0 = tid >> 3;    // row 0..31 (strided by 32 for 4 rows/thread)
    const int wave = tid >> 6, lane = tid & 63;
    const int wm = wave >> 1, wn = wave & 1;
    const int r16 = lane & 15, quad = lane >> 4;

    f32x4v acc[4][4];
#pragma unroll
    for (int mi = 0; mi < 4; ++mi)
#pragma unroll
        for (int ni = 0; ni < 4; ++ni)
            acc[mi][ni] = (f32x4v){0.f, 0.f, 0.f, 0.f};

    for (int k0 = 0; k0 < 512; k0 += 32) {
#pragma unroll
        for (int rr = 0; rr < 4; ++rr) {
            const int r = r0 + rr * 32;
            const float4 av = *(const float4*)(g.A + (size_t)(m0 + r) * 512 + k0 + kc * 4);
            const float4 wv = *(const float4*)(g.W + (size_t)(n0 + r) * 512 + k0 + kc * 4);
            u16x4 ap = { bf16u(av.x), bf16u(av.y), bf16u(av.z), bf16u(av.w) };
            u16x4 wp = { bf16u(wv.x), bf16u(wv.y), bf16u(wv.z), bf16u(wv.w) };
            *(u16x4*)(As + r * 40 + kc * 4) = ap;
            *(u16x4*)(Ws + r * 40 + kc * 4) = wp;
        }
        __syncthreads();

        bf16x8 af[4], bfr[4];
#pragma unroll
        for (int mi = 0; mi < 4; ++mi)
            af[mi] = *(const bf16x8*)(As + (wm * 64 + mi * 16 + r16) * 40 + quad * 8);
#pragma unroll
        for (int ni = 0; ni < 4; ++ni)
            bfr[ni] = *(const bf16x8*)(Ws + (wn * 64 + ni * 16 + r16) * 40 + quad * 8);
#pragma unroll
        for (int mi = 0; mi < 4; ++mi)
#pragma unroll
            for (int ni = 0; ni < 4; ++ni)
                acc[mi][ni] = __builtin_amdgcn_mfma_f32_16x16x32_bf16(af[mi], bfr[ni], acc[mi][ni], 0, 0, 0);
        __syncthreads();
    }

#pragma unroll
    for (int ni = 0; ni < 4; ++ni) {
        const int col = n0 + wn * 64 + ni * 16 + r16;
        const float bv = g.bias[col];
#pragma unroll
        for (int mi = 0; mi < 4; ++mi) {
#pragma unroll
            for (int i = 0; i < 4; ++i) {
                const int row = m0 + wm * 64 + mi * 16 + quad * 4 + i;
                g.out[(size_t)row * 512 + col] = (acc[mi][ni][i] + bv) * g.scale;
            }
        }
    }
}

// ---------------------------------------------------------------------------
// Fused attention with ONLINE SOFTMAX (chunk-wise running max, unconditional
// per-chunk rescale). Masked scores are ~ -8000 for many rows, so a true
// running max is REQUIRED (fixed-reference exp underflows the whole row).
// grid: (L/64, H, B)  block: 256 (4 waves; each wave covers 256 keys)
// ---------------------------------------------------------------------------
#define KCHUNK 16

__global__ __launch_bounds__(256) void attn_kernel(
    const float* __restrict__ qp, const float* __restrict__ kp, const float* __restrict__ vp,
    const float* __restrict__ probs_q, const float* __restrict__ probs_k,
    const float* __restrict__ padding_mask, float* __restrict__ attn_out)
{
    const int tid = threadIdx.x, lane = tid & 63, w = tid >> 6;
    const int b = blockIdx.z, h = blockIdx.y;
    const int l = blockIdx.x * 64 + lane;

    const float4* qv = (const float4*)(qp + ((size_t)(b * NL + l)) * ND + h * NDK);
    float4 qr[16];
#pragma unroll
    for (int i = 0; i < 16; ++i) qr[i] = qv[i];

    const float* pqp = probs_q + ((size_t)((b * NH + h) * NL + l)) * NC;
    const float4 pq0 = ((const float4*)pqp)[0];
    const float4 pq1 = ((const float4*)pqp)[1];

    float4 accv[16];
#pragma unroll
    for (int i = 0; i < 16; ++i) accv[i] = make_float4(0.f, 0.f, 0.f, 0.f);
    float lsum = 0.f;
    float m = -1e30f;

    const float* pmb = padding_mask + b * NL;
    const int kbeg = w * 256, kend = kbeg + 256;

    for (int kc0 = kbeg; kc0 < kend; kc0 += KCHUNK) {
        float sc[KCHUNK], cmv[KCHUNK];
        float cmax = -1e30f;
#pragma unroll
        for (int j = 0; j < KCHUNK; ++j) {
            const int k = kc0 + j;
            const float4* kr = (const float4*)(kp + ((size_t)(b * NL + k)) * ND + h * NDK);
            float s = 0.f;
#pragma unroll
            for (int i = 0; i < 16; ++i) {
                float4 kv = kr[i];
                s = fmaf(qr[i].x, kv.x, s); s = fmaf(qr[i].y, kv.y, s);
                s = fmaf(qr[i].z, kv.z, s); s = fmaf(qr[i].w, kv.w, s);
            }
            const float4* pkp = (const float4*)(probs_k + ((size_t)((b * NH + h) * NL + k)) * NC);
            const float4 pk0 = pkp[0], pk1 = pkp[1];
            float sim = pq0.x * pk0.x + pq0.y * pk0.y + pq0.z * pk0.z + pq0.w * pk0.w
                      + pq1.x * pk1.x + pq1.y * pk1.y + pq1.z * pk1.z + pq1.w * pk1.w;
            float cm = 1.f - sim + pmb[k];
            cm = fminf(fmaxf(cm, 0.f), 1.f);
            cmv[j] = cm;
            sc[j] = s - 10000.f * cm;
            cmax = fmaxf(cmax, sc[j]);
        }
        // merge chunk max into running max; rescale previous accumulation
        const float mnew = fmaxf(m, cmax);
        const float r = __expf(m - mnew);    // first chunk: exp(-1e30-x) -> 0, acc/lsum are 0 anyway
        m = mnew;
        lsum *= r;
#pragma unroll
        for (int i = 0; i < 16; ++i) {
            accv[i].x *= r; accv[i].y *= r; accv[i].z *= r; accv[i].w *= r;
        }
#pragma unroll
        for (int j = 0; j < KCHUNK; ++j) {
            const int k = kc0 + j;
            const float ex = __expf(sc[j] - m);
            lsum += ex;
            const float pw = ex * (1.f - cmv[j]);
            const float4* vr = (const float4*)(vp + ((size_t)(b * NL + k)) * ND + h * NDK);
#pragma unroll
            for (int i = 0; i < 16; ++i) {
                float4 vv = vr[i];
                accv[i].x = fmaf(pw, vv.x, accv[i].x); accv[i].y = fmaf(pw, vv.y, accv[i].y);
                accv[i].z = fmaf(pw, vv.z, accv[i].z); accv[i].w = fmaf(pw, vv.w, accv[i].w);
            }
        }
    }

    // cross-wave merge with per-wave (m, l, acc): waves 1..3 publish, wave 0 merges
    __shared__ float red[3][64 * 68];
    if (w > 0) {
        float* dst = &red[w - 1][lane * 68];
#pragma unroll
        for (int i = 0; i < 16; ++i) {
            dst[i * 4 + 0] = accv[i].x; dst[i * 4 + 1] = accv[i].y;
            dst[i * 4 + 2] = accv[i].z; dst[i * 4 + 3] = accv[i].w;
        }
        dst[64] = lsum;
        dst[65] = m;
    }
    __syncthreads();
    if (w == 0) {
        float M = m;
#pragma unroll
        for (int wv = 0; wv < 3; ++wv) M = fmaxf(M, red[wv][lane * 68 + 65]);
        const float r0 = __expf(m - M);
        lsum *= r0;
#pragma unroll
        for (int i = 0; i < 16; ++i) {
            accv[i].x *= r0; accv[i].y *= r0; accv[i].z *= r0; accv[i].w *= r0;
        }
#pragma unroll
        for (int wv = 0; wv < 3; ++wv) {
            const float* sp = &red[wv][lane * 68];
            const float rw = __expf(sp[65] - M);
            lsum += sp[64] * rw;
#pragma unroll
            for (int i = 0; i < 16; ++i) {
                accv[i].x = fmaf(rw, sp[i * 4 + 0], accv[i].x);
                accv[i].y = fmaf(rw, sp[i * 4 + 1], accv[i].y);
                accv[i].z = fmaf(rw, sp[i * 4 + 2], accv[i].z);
                accv[i].w = fmaf(rw, sp[i * 4 + 3], accv[i].w);
            }
        }
        const float inv = 1.f / lsum;
        float4* op = (float4*)(attn_out + ((size_t)(b * NL + l)) * ND + h * NDK);
#pragma unroll
        for (int i = 0; i < 16; ++i) {
            float4 o;
            o.x = accv[i].x * inv; o.y = accv[i].y * inv;
            o.z = accv[i].z * inv; o.w = accv[i].w * inv;
            op[i] = o;
        }
    }
}

// ---------------------------------------------------------------------------
// Finalize scalars: kl_loss[b], div_loss[b]
// ---------------------------------------------------------------------------
__global__ void finalize_kernel(const float* __restrict__ acc_kl, const float* __restrict__ acc_div,
                                const float* __restrict__ Gacc, float* __restrict__ out_tail)
{
    const int b = threadIdx.x;
    if (b < NB) {
        float gsum = 0.f;
        for (int s = 0; s < 2; ++s)
            for (int i = 0; i < 512; ++i) {
                float g = Gacc[s * 2048 + b * 512 + i];
                gsum = fmaf(g, g, gsum);
            }
        out_tail[b]      = acc_kl[b] * (1.0f / 8192.0f) + 2.0f * KL3_CONST;   // /(H*L) + 2*kl3
        out_tail[4 + b]  = (acc_div[b] + 0.75f * gsum) * (1.0f / 8388608.0f); // /(H*L*L)
    }
}

// ---------------------------------------------------------------------------
extern "C" void kernel_launch(void* const* d_in, const int* in_sizes, int n_in,
                              void* d_out, int out_size, void* d_ws, size_t ws_size,
                              hipStream_t stream)
{
    const float* query        = (const float*)d_in[0];
    const float* key          = (const float*)d_in[1];
    const float* value        = (const float*)d_in[2];
    const float* padding_mask = (const float*)d_in[3];
    const float* Wq = (const float*)d_in[4];
    const float* bq = (const float*)d_in[5];
    const float* Wk = (const float*)d_in[6];
    const float* bk = (const float*)d_in[7];
    const float* Wv = (const float*)d_in[8];
    const float* bv = (const float*)d_in[9];
    const float* Wo = (const float*)d_in[10];
    const float* bo = (const float*)d_in[11];
    const float* tok_mu        = (const float*)d_in[12];
    const float* tok_log_var   = (const float*)d_in[13];
    const float* tok_log_prior = (const float*)d_in[14];

    float* ws = (float*)d_ws;
    const size_t NMAT = (size_t)NB * NL * ND;   // 2097152
    float* qp      = ws;
    float* kp      = qp + NMAT;
    float* vp      = kp + NMAT;
    float* ao      = vp + NMAT;
    float* probs_q = ao + NMAT;                 // 262144
    float* probs_k = probs_q + (size_t)NB * NH * NL * NC;
    float* acc_kl  = probs_k + (size_t)NB * NH * NL * NC;
    float* acc_div = acc_kl + 4;
    float* Gacc    = acc_div + 4;               // 2*B*H*64 = 4096

    hipMemsetAsync(acc_kl, 0, (4 + 4 + 4096) * sizeof(float), stream);

    cluster_kernel<<<dim3(NL / 256, NB * NH, 2), 256, 0, stream>>>(
        query, key, tok_mu, tok_log_var, tok_log_prior,
        probs_q, probs_k, acc_kl, acc_div, Gacc);

    GemmArgs gq{query, Wq, bq, qp, 0.125f};  // /sqrt(Dk) folded into epilogue
    GemmArgs gk{key,   Wk, bk, kp, 1.f};
    GemmArgs gv{value, Wv, bv, vp, 1.f};
    gemm_bt<<<dim3(4, 32, 3), 256, 0, stream>>>(gq, gk, gv);

    attn_kernel<<<dim3(NL / 64, NH, NB), 256, 0, stream>>>(
        qp, kp, vp, probs_q, probs_k, padding_mask, ao);

    GemmArgs go{ao, Wo, bo, (float*)d_out, 1.f};
    gemm_bt<<<dim3(4, 32, 1), 256, 0, stream>>>(go, go, go);

    finalize_kernel<<<1, 64, 0, stream>>>(acc_kl, acc_div, Gacc, (float*)d_out + NMAT);
}

// Round 3
// 230.556 us; speedup vs baseline: 5.5340x; 5.5340x over previous
//
#include <hip/hip_runtime.h>
#include <hip/hip_bf16.h>
#include <math.h>

// Problem constants: B=4, L=1024, D=512, H=8, C=8, Dk=64
#define NB 4
#define NL 1024
#define ND 512
#define NH 8
#define NC 8
#define NDK 64

static constexpr float KL3_CONST = 115.36544595161891f; // -0.5*(1+ln0.01)*64, per clustering call

typedef __bf16 bf16x8 __attribute__((ext_vector_type(8)));
typedef float  f32x4v __attribute__((ext_vector_type(4)));
typedef unsigned short u16x4 __attribute__((ext_vector_type(4)));

__device__ __forceinline__ unsigned short bf16u(float f) {
    return __builtin_bit_cast(unsigned short, (__bf16)f);
}

// ---------------------------------------------------------------------------
// Clustering: probs (softmax over C of gaussian log-pdf), kl partials, div
// diag partials, and Gram matrix G = P^T P (C x C) per (b,h,side).
// grid: (L/256, B*H, 2)  block: 256
// ---------------------------------------------------------------------------
__global__ __launch_bounds__(256) void cluster_kernel(
    const float* __restrict__ query, const float* __restrict__ key,
    const float* __restrict__ tok_mu, const float* __restrict__ tok_log_var,
    const float* __restrict__ tok_log_prior,
    float* __restrict__ probs_q, float* __restrict__ probs_k,
    float* __restrict__ acc_kl, float* __restrict__ acc_div,
    float* __restrict__ Gacc)
{
    const int tid  = threadIdx.x;
    const int bh   = blockIdx.y;
    const int b    = bh >> 3, h = bh & 7;
    const int side = blockIdx.z;
    const float* src = side ? key : query;
    float* probs_out = side ? probs_k : probs_q;

    __shared__ alignas(16) float mu_s[512];
    __shared__ alignas(16) float iv_s[512];
    __shared__ float lvsum_s[8], alpha_s[8], logp_s[8], prior_s[8];
    __shared__ float Pl[256 * 9];     // probs per-thread, stride 9 (bank-spread)
    __shared__ float Gpart[4][64];
    __shared__ float red_s[8];

    for (int i = tid; i < 512; i += 256) {
        mu_s[i] = tok_mu[h * 512 + i];
        float lv = tok_log_var[h * 512 + i];
        iv_s[i] = __expf(-lv);
    }
    if (tid < 8) {
        float ls = 0.f, al = 0.f;
        for (int d = 0; d < 64; ++d) {
            float lv = tok_log_var[(h * 8 + tid) * 64 + d];
            ls += lv;
            al += 0.01f * __expf(-lv) + lv;   // avar/var + lv, avar = exp(ln .01)
        }
        lvsum_s[tid] = ls; alpha_s[tid] = al;
    }
    if (tid == 0) {
        float lp[8]; float mx = -1e30f;
        for (int c = 0; c < 8; ++c) { lp[c] = tok_log_prior[h * 8 + c]; mx = fmaxf(mx, lp[c]); }
        float se = 0.f;
        for (int c = 0; c < 8; ++c) se += __expf(lp[c] - mx);
        float lse = mx + __logf(se);
        for (int c = 0; c < 8; ++c) { logp_s[c] = lp[c] - lse; prior_s[c] = __expf(lp[c] - lse); }
    }
    __syncthreads();

    const int l = blockIdx.x * 256 + tid;
    const float4* xp = (const float4*)(src + ((size_t)(b * NL + l)) * ND + h * NDK);
    float4 xr[16];
#pragma unroll
    for (int i = 0; i < 16; ++i) xr[i] = xp[i];

    float ms[8];
#pragma unroll
    for (int c = 0; c < 8; ++c) {
        const float4* mc = (const float4*)(mu_s + c * 64);
        const float4* ic = (const float4*)(iv_s + c * 64);
        float s = 0.f;
#pragma unroll
        for (int i = 0; i < 16; ++i) {
            float4 m4 = mc[i], v4 = ic[i], x4 = xr[i];
            float dx = x4.x - m4.x; s = fmaf(dx * dx, v4.x, s);
            float dy = x4.y - m4.y; s = fmaf(dy * dy, v4.y, s);
            float dz = x4.z - m4.z; s = fmaf(dz * dz, v4.z, s);
            float dw = x4.w - m4.w; s = fmaf(dw * dw, v4.w, s);
        }
        ms[c] = s;
    }

    float lpdf[8]; float mx = -1e30f;
#pragma unroll
    for (int c = 0; c < 8; ++c) {
        lpdf[c] = -0.5f * (ms[c] + lvsum_s[c]) + logp_s[c];
        mx = fmaxf(mx, lpdf[c]);
    }
    float e[8]; float se = 0.f;
#pragma unroll
    for (int c = 0; c < 8; ++c) { e[c] = __expf(lpdf[c] - mx); se += e[c]; }
    float lse = __logf(se);
    float inv = 1.f / se;
    float p[8]; float kl1 = 0.f, kl2 = 0.f, sqq = 0.f;
#pragma unroll
    for (int c = 0; c < 8; ++c) {
        p[c] = e[c] * inv;
        float logprob = lpdf[c] - mx - lse;
        kl1 += prior_s[c] * (logp_s[c] - logprob);
        kl2 += p[c] * (ms[c] + alpha_s[c]);
        sqq = fmaf(p[c], p[c], sqq);
    }

    float* po = probs_out + ((size_t)((b * NH + h) * NL + l)) * NC;
    ((float4*)po)[0] = make_float4(p[0], p[1], p[2], p[3]);
    ((float4*)po)[1] = make_float4(p[4], p[5], p[6], p[7]);
#pragma unroll
    for (int c = 0; c < 8; ++c) Pl[tid * 9 + c] = p[c];

    float dterm = 1.25f * (sqq - 1.f) * (sqq - 1.f) - 0.75f * sqq * sqq;
    float klv = kl1 + 0.5f * kl2;
    __syncthreads();

    // Gram partials: thread (qt,pos) sums P[l][c1]*P[l][c2] over its quarter
    {
        int qt = tid >> 6, pos = tid & 63, c1 = pos >> 3, c2 = pos & 7;
        float g = 0.f;
        for (int i = 0; i < 64; ++i) {
            int ll = qt * 64 + i;
            g = fmaf(Pl[ll * 9 + c1], Pl[ll * 9 + c2], g);
        }
        Gpart[qt][pos] = g;
    }

    // block reduce kl and div-diag partials
#pragma unroll
    for (int o = 32; o > 0; o >>= 1) {
        klv   += __shfl_down(klv, o);
        dterm += __shfl_down(dterm, o);
    }
    if ((tid & 63) == 0) { red_s[tid >> 6] = klv; red_s[4 + (tid >> 6)] = dterm; }
    __syncthreads();
    if (tid == 0) {
        atomicAdd(acc_kl + b,  red_s[0] + red_s[1] + red_s[2] + red_s[3]);
        atomicAdd(acc_div + b, red_s[4] + red_s[5] + red_s[6] + red_s[7]);
    }
    if (tid < 64) {
        float g = Gpart[0][tid] + Gpart[1][tid] + Gpart[2][tid] + Gpart[3][tid];
        atomicAdd(Gacc + ((size_t)((side * NB + b) * NH + h)) * 64 + tid, g);
    }
}

// ---------------------------------------------------------------------------
// bf16 MFMA GEMM: out = (A @ W^T + bias) * scale.  A:[M,512] W:[512,512] row=N
// 128x128 tile, BK=32, 4 waves (2x2), each wave 4x4 of 16x16x32 MFMA tiles.
// fp32 inputs converted to bf16 during LDS staging. grid: (4, M/128, nbatch)
// ---------------------------------------------------------------------------
struct GemmArgs { const float* A; const float* W; const float* bias; float* out; float scale; };

__global__ __launch_bounds__(256) void gemm_bt(GemmArgs g0, GemmArgs g1, GemmArgs g2)
{
    GemmArgs g = (blockIdx.z == 0) ? g0 : ((blockIdx.z == 1) ? g1 : g2);
    const int tid = threadIdx.x;
    const int n0 = blockIdx.x * 128, m0 = blockIdx.y * 128;

    __shared__ alignas(16) unsigned short As[128 * 40];  // stride 40 to break conflicts
    __shared__ alignas(16) unsigned short Ws[128 * 40];

    const int kc = tid & 7;     // k-chunk (float4) 0..7
    const int r0 = tid >> 3;    // row 0..31 (strided by 32 for 4 rows/thread)
    const int wave = tid >> 6, lane = tid & 63;
    const int wm = wave >> 1, wn = wave & 1;
    const int r16 = lane & 15, quad = lane >> 4;

    f32x4v acc[4][4];
#pragma unroll
    for (int mi = 0; mi < 4; ++mi)
#pragma unroll
        for (int ni = 0; ni < 4; ++ni)
            acc[mi][ni] = (f32x4v){0.f, 0.f, 0.f, 0.f};

    for (int k0 = 0; k0 < 512; k0 += 32) {
#pragma unroll
        for (int rr = 0; rr < 4; ++rr) {
            const int r = r0 + rr * 32;
            const float4 av = *(const float4*)(g.A + (size_t)(m0 + r) * 512 + k0 + kc * 4);
            const float4 wv = *(const float4*)(g.W + (size_t)(n0 + r) * 512 + k0 + kc * 4);
            u16x4 ap = { bf16u(av.x), bf16u(av.y), bf16u(av.z), bf16u(av.w) };
            u16x4 wp = { bf16u(wv.x), bf16u(wv.y), bf16u(wv.z), bf16u(wv.w) };
            *(u16x4*)(As + r * 40 + kc * 4) = ap;
            *(u16x4*)(Ws + r * 40 + kc * 4) = wp;
        }
        __syncthreads();

        bf16x8 af[4], bfr[4];
#pragma unroll
        for (int mi = 0; mi < 4; ++mi)
            af[mi] = *(const bf16x8*)(As + (wm * 64 + mi * 16 + r16) * 40 + quad * 8);
#pragma unroll
        for (int ni = 0; ni < 4; ++ni)
            bfr[ni] = *(const bf16x8*)(Ws + (wn * 64 + ni * 16 + r16) * 40 + quad * 8);
#pragma unroll
        for (int mi = 0; mi < 4; ++mi)
#pragma unroll
            for (int ni = 0; ni < 4; ++ni)
                acc[mi][ni] = __builtin_amdgcn_mfma_f32_16x16x32_bf16(af[mi], bfr[ni], acc[mi][ni], 0, 0, 0);
        __syncthreads();
    }

#pragma unroll
    for (int ni = 0; ni < 4; ++ni) {
        const int col = n0 + wn * 64 + ni * 16 + r16;
        const float bv = g.bias[col];
#pragma unroll
        for (int mi = 0; mi < 4; ++mi) {
#pragma unroll
            for (int i = 0; i < 4; ++i) {
                const int row = m0 + wm * 64 + mi * 16 + quad * 4 + i;
                g.out[(size_t)row * 512 + col] = (acc[mi][ni][i] + bv) * g.scale;
            }
        }
    }
}

// ---------------------------------------------------------------------------
// MFMA flash attention. Block = 64 q-rows of one (b,h); 4 waves, each owns a
// 16-row q strip and ALL keys. Loop over 16 K-tiles of 64 keys:
//   S = Q K^T via mfma_16x16x32_bf16 (Q A-frags in regs, K staged bf16 LDS)
//   sim = probs_q . probs_k in fp32 VALU (bf16 would shift scores by ~40 via
//         the -10000*cm term and scramble the softmax)
//   online softmax in C-layout (shfl over 16-lane quad group)
//   P' -> per-wave LDS (bf16) -> A-frags; O += P' V via MFMA (V transposed in
//         LDS so B-frags are single ds_read_b128)
// grid: (L/64, H, B)  block: 256
// ---------------------------------------------------------------------------
#define APAD 72   // u16 stride: 144B rows -> 16B-aligned b128, balanced banks

__global__ __launch_bounds__(256) void attn_mfma_kernel(
    const float* __restrict__ qp, const float* __restrict__ kp, const float* __restrict__ vp,
    const float* __restrict__ probs_q, const float* __restrict__ probs_k,
    const float* __restrict__ padding_mask, float* __restrict__ attn_out)
{
    const int tid = threadIdx.x, lane = tid & 63, w = tid >> 6;
    const int r16 = lane & 15, quad = lane >> 4;
    const int b = blockIdx.z, h = blockIdx.y;
    const int qbase = blockIdx.x * 64;

    __shared__ alignas(16) unsigned short Ks[64 * APAD];
    __shared__ alignas(16) unsigned short Vt[64 * APAD];     // Vt[dim][key]
    __shared__ alignas(16) unsigned short Ps[4][16 * APAD];  // per-wave P'
    __shared__ float pk_s[8][65];                            // pk_s[c][key]
    __shared__ float pm_s[64];

    // Q A-frags (row = lane&15 of wave strip, dims quad*8 + 32*kstep), once.
    bf16x8 qa[2];
    {
        const float* qrow = qp + ((size_t)(b * NL + qbase + w * 16 + r16)) * ND + h * NDK + quad * 8;
#pragma unroll
        for (int ks = 0; ks < 2; ++ks) {
            float4 f0 = *(const float4*)(qrow + ks * 32);
            float4 f1 = *(const float4*)(qrow + ks * 32 + 4);
            qa[ks] = (bf16x8){(__bf16)f0.x, (__bf16)f0.y, (__bf16)f0.z, (__bf16)f0.w,
                              (__bf16)f1.x, (__bf16)f1.y, (__bf16)f1.z, (__bf16)f1.w};
        }
    }
    // probs_q rows for this lane's C-layout rows (quad*4+i), fp32, once.
    float pq[4][8];
#pragma unroll
    for (int i = 0; i < 4; ++i) {
        const float* pr = probs_q + ((size_t)((b * NH + h) * NL + qbase + w * 16 + quad * 4 + i)) * NC;
        float4 a = ((const float4*)pr)[0], c = ((const float4*)pr)[1];
        pq[i][0] = a.x; pq[i][1] = a.y; pq[i][2] = a.z; pq[i][3] = a.w;
        pq[i][4] = c.x; pq[i][5] = c.y; pq[i][6] = c.z; pq[i][7] = c.w;
    }

    f32x4v oacc[4];
#pragma unroll
    for (int n = 0; n < 4; ++n) oacc[n] = (f32x4v){0.f, 0.f, 0.f, 0.f};
    float m_i[4] = {-1e30f, -1e30f, -1e30f, -1e30f};
    float l_i[4] = {0.f, 0.f, 0.f, 0.f};

    for (int kt = 0; kt < 16; ++kt) {
        const int key0 = kt * 64;
        // ---- stage K (row-major) and V (transposed) as bf16, pk, pm ----
        {
            const int skey = tid >> 2, dc = tid & 3;
            const float* krow = kp + ((size_t)(b * NL + key0 + skey)) * ND + h * NDK + dc * 16;
            const float* vrow = vp + ((size_t)(b * NL + key0 + skey)) * ND + h * NDK + dc * 16;
#pragma unroll
            for (int jj = 0; jj < 4; ++jj) {
                float4 kv = *(const float4*)(krow + jj * 4);
                u16x4 kb = { bf16u(kv.x), bf16u(kv.y), bf16u(kv.z), bf16u(kv.w) };
                *(u16x4*)(Ks + skey * APAD + dc * 16 + jj * 4) = kb;
                float4 vv = *(const float4*)(vrow + jj * 4);
                const int d0 = dc * 16 + jj * 4;
                Vt[(d0 + 0) * APAD + skey] = bf16u(vv.x);
                Vt[(d0 + 1) * APAD + skey] = bf16u(vv.y);
                Vt[(d0 + 2) * APAD + skey] = bf16u(vv.z);
                Vt[(d0 + 3) * APAD + skey] = bf16u(vv.w);
            }
            if (tid < 128) {
                const int pkey = tid >> 1, cc = (tid & 1) * 4;
                float4 p = *(const float4*)(probs_k + ((size_t)((b * NH + h) * NL + key0 + pkey)) * NC + cc);
                pk_s[cc + 0][pkey] = p.x; pk_s[cc + 1][pkey] = p.y;
                pk_s[cc + 2][pkey] = p.z; pk_s[cc + 3][pkey] = p.w;
            }
            if (tid < 64) pm_s[tid] = padding_mask[b * NL + key0 + tid];
        }
        __syncthreads();

        // ---- S = Q K^T : 4 key sub-tiles of 16 ----
        f32x4v sacc[4];
#pragma unroll
        for (int t = 0; t < 4; ++t) {
            sacc[t] = (f32x4v){0.f, 0.f, 0.f, 0.f};
            bf16x8 kb0 = *(const bf16x8*)(Ks + (t * 16 + r16) * APAD + quad * 8);
            bf16x8 kb1 = *(const bf16x8*)(Ks + (t * 16 + r16) * APAD + 32 + quad * 8);
            sacc[t] = __builtin_amdgcn_mfma_f32_16x16x32_bf16(qa[0], kb0, sacc[t], 0, 0, 0);
            sacc[t] = __builtin_amdgcn_mfma_f32_16x16x32_bf16(qa[1], kb1, sacc[t], 0, 0, 0);
        }

        // ---- sim (fp32) + mask; C-layout element (t,i): q=quad*4+i, key=t*16+r16
        float sc[4][4], wgt[4][4];
#pragma unroll
        for (int t = 0; t < 4; ++t) {
            const int keyl = t * 16 + r16;
            float pkc[8];
#pragma unroll
            for (int c = 0; c < 8; ++c) pkc[c] = pk_s[c][keyl];
            const float pmv = pm_s[keyl];
#pragma unroll
            for (int i = 0; i < 4; ++i) {
                float sim = 0.f;
#pragma unroll
                for (int c = 0; c < 8; ++c) sim = fmaf(pq[i][c], pkc[c], sim);
                float cm = 1.f - sim + pmv;
                cm = fminf(fmaxf(cm, 0.f), 1.f);
                sc[t][i] = sacc[t][i] - 10000.f * cm;
                wgt[t][i] = 1.f - cm;
            }
        }

        // ---- online softmax: row stats across the 16-lane quad group ----
        float mx[4];
#pragma unroll
        for (int i = 0; i < 4; ++i)
            mx[i] = fmaxf(fmaxf(sc[0][i], sc[1][i]), fmaxf(sc[2][i], sc[3][i]));
#pragma unroll
        for (int o = 1; o < 16; o <<= 1) {
#pragma unroll
            for (int i = 0; i < 4; ++i) mx[i] = fmaxf(mx[i], __shfl_xor(mx[i], o));
        }
        float rr[4];
#pragma unroll
        for (int i = 0; i < 4; ++i) {
            const float mnew = fmaxf(m_i[i], mx[i]);
            rr[i] = __expf(m_i[i] - mnew);
            m_i[i] = mnew;
            l_i[i] *= rr[i];
        }
#pragma unroll
        for (int n = 0; n < 4; ++n) {
            oacc[n][0] *= rr[0]; oacc[n][1] *= rr[1];
            oacc[n][2] *= rr[2]; oacc[n][3] *= rr[3];
        }
        float lad[4] = {0.f, 0.f, 0.f, 0.f};
#pragma unroll
        for (int t = 0; t < 4; ++t) {
#pragma unroll
            for (int i = 0; i < 4; ++i) {
                const float p = __expf(sc[t][i] - m_i[i]);
                lad[i] += p;
                Ps[w][(quad * 4 + i) * APAD + t * 16 + r16] = bf16u(p * wgt[t][i]);
            }
        }
#pragma unroll
        for (int o = 1; o < 16; o <<= 1) {
#pragma unroll
            for (int i = 0; i < 4; ++i) lad[i] += __shfl_xor(lad[i], o);
        }
#pragma unroll
        for (int i = 0; i < 4; ++i) l_i[i] += lad[i];

        // ---- O += P' V  (A from Ps, B from Vt) ----
        bf16x8 pa0 = *(const bf16x8*)(Ps[w] + r16 * APAD + quad * 8);
        bf16x8 pa1 = *(const bf16x8*)(Ps[w] + r16 * APAD + 32 + quad * 8);
#pragma unroll
        for (int n = 0; n < 4; ++n) {
            bf16x8 vb0 = *(const bf16x8*)(Vt + (n * 16 + r16) * APAD + quad * 8);
            bf16x8 vb1 = *(const bf16x8*)(Vt + (n * 16 + r16) * APAD + 32 + quad * 8);
            oacc[n] = __builtin_amdgcn_mfma_f32_16x16x32_bf16(pa0, vb0, oacc[n], 0, 0, 0);
            oacc[n] = __builtin_amdgcn_mfma_f32_16x16x32_bf16(pa1, vb1, oacc[n], 0, 0, 0);
        }
        __syncthreads();
    }

    // ---- epilogue: O / l ----
#pragma unroll
    for (int i = 0; i < 4; ++i) {
        const float inv = 1.f / l_i[i];
        const int q = qbase + w * 16 + quad * 4 + i;
        float* orow = attn_out + ((size_t)(b * NL + q)) * ND + h * NDK;
#pragma unroll
        for (int n = 0; n < 4; ++n) orow[n * 16 + r16] = oacc[n][i] * inv;
    }
}

// ---------------------------------------------------------------------------
// Finalize scalars: kl_loss[b], div_loss[b]
// ---------------------------------------------------------------------------
__global__ void finalize_kernel(const float* __restrict__ acc_kl, const float* __restrict__ acc_div,
                                const float* __restrict__ Gacc, float* __restrict__ out_tail)
{
    const int b = threadIdx.x;
    if (b < NB) {
        float gsum = 0.f;
        for (int s = 0; s < 2; ++s)
            for (int i = 0; i < 512; ++i) {
                float g = Gacc[s * 2048 + b * 512 + i];
                gsum = fmaf(g, g, gsum);
            }
        out_tail[b]      = acc_kl[b] * (1.0f / 8192.0f) + 2.0f * KL3_CONST;   // /(H*L) + 2*kl3
        out_tail[4 + b]  = (acc_div[b] + 0.75f * gsum) * (1.0f / 8388608.0f); // /(H*L*L)
    }
}

// ---------------------------------------------------------------------------
extern "C" void kernel_launch(void* const* d_in, const int* in_sizes, int n_in,
                              void* d_out, int out_size, void* d_ws, size_t ws_size,
                              hipStream_t stream)
{
    const float* query        = (const float*)d_in[0];
    const float* key          = (const float*)d_in[1];
    const float* value        = (const float*)d_in[2];
    const float* padding_mask = (const float*)d_in[3];
    const float* Wq = (const float*)d_in[4];
    const float* bq = (const float*)d_in[5];
    const float* Wk = (const float*)d_in[6];
    const float* bk = (const float*)d_in[7];
    const float* Wv = (const float*)d_in[8];
    const float* bv = (const float*)d_in[9];
    const float* Wo = (const float*)d_in[10];
    const float* bo = (const float*)d_in[11];
    const float* tok_mu        = (const float*)d_in[12];
    const float* tok_log_var   = (const float*)d_in[13];
    const float* tok_log_prior = (const float*)d_in[14];

    float* ws = (float*)d_ws;
    const size_t NMAT = (size_t)NB * NL * ND;   // 2097152
    float* qp      = ws;
    float* kp      = qp + NMAT;
    float* vp      = kp + NMAT;
    float* ao      = vp + NMAT;
    float* probs_q = ao + NMAT;                 // 262144
    float* probs_k = probs_q + (size_t)NB * NH * NL * NC;
    float* acc_kl  = probs_k + (size_t)NB * NH * NL * NC;
    float* acc_div = acc_kl + 4;
    float* Gacc    = acc_div + 4;               // 2*B*H*64 = 4096

    hipMemsetAsync(acc_kl, 0, (4 + 4 + 4096) * sizeof(float), stream);

    cluster_kernel<<<dim3(NL / 256, NB * NH, 2), 256, 0, stream>>>(
        query, key, tok_mu, tok_log_var, tok_log_prior,
        probs_q, probs_k, acc_kl, acc_div, Gacc);

    GemmArgs gq{query, Wq, bq, qp, 0.125f};  // /sqrt(Dk) folded into epilogue
    GemmArgs gk{key,   Wk, bk, kp, 1.f};
    GemmArgs gv{value, Wv, bv, vp, 1.f};
    gemm_bt<<<dim3(4, 32, 3), 256, 0, stream>>>(gq, gk, gv);

    attn_mfma_kernel<<<dim3(NL / 64, NH, NB), 256, 0, stream>>>(
        qp, kp, vp, probs_q, probs_k, padding_mask, ao);

    GemmArgs go{ao, Wo, bo, (float*)d_out, 1.f};
    gemm_bt<<<dim3(4, 32, 1), 256, 0, stream>>>(go, go, go);

    finalize_kernel<<<1, 64, 0, stream>>>(acc_kl, acc_div, Gacc, (float*)d_out + NMAT);
}

// Round 4
// 223.363 us; speedup vs baseline: 5.7122x; 1.0322x over previous
//
#include <hip/hip_runtime.h>
#include <hip/hip_bf16.h>
#include <math.h>

// Problem constants: B=4, L=1024, D=512, H=8, C=8, Dk=64
#define NB 4
#define NL 1024
#define ND 512
#define NH 8
#define NC 8
#define NDK 64

static constexpr float KL3_CONST = 115.36544595161891f; // -0.5*(1+ln0.01)*64, per clustering call

typedef __bf16 bf16x8 __attribute__((ext_vector_type(8)));
typedef float  f32x4v __attribute__((ext_vector_type(4)));
typedef unsigned short u16x4 __attribute__((ext_vector_type(4)));
typedef unsigned short u16x8 __attribute__((ext_vector_type(8)));

__device__ __forceinline__ unsigned short bf16u(float f) {
    return __builtin_bit_cast(unsigned short, (__bf16)f);
}

// ---------------------------------------------------------------------------
// Clustering: probs (softmax over C of gaussian log-pdf), kl partials, div
// diag partials, and Gram matrix G = P^T P (C x C) per (b,h,side).
// grid: (L/256, B*H, 2)  block: 256
// ---------------------------------------------------------------------------
__global__ __launch_bounds__(256) void cluster_kernel(
    const float* __restrict__ query, const float* __restrict__ key,
    const float* __restrict__ tok_mu, const float* __restrict__ tok_log_var,
    const float* __restrict__ tok_log_prior,
    float* __restrict__ probs_q, float* __restrict__ probs_k,
    float* __restrict__ acc_kl, float* __restrict__ acc_div,
    float* __restrict__ Gacc)
{
    const int tid  = threadIdx.x;
    const int bh   = blockIdx.y;
    const int b    = bh >> 3, h = bh & 7;
    const int side = blockIdx.z;
    const float* src = side ? key : query;
    float* probs_out = side ? probs_k : probs_q;

    __shared__ alignas(16) float mu_s[512];
    __shared__ alignas(16) float iv_s[512];
    __shared__ float lvsum_s[8], alpha_s[8], logp_s[8], prior_s[8];
    __shared__ float Pl[256 * 9];
    __shared__ float Gpart[4][64];
    __shared__ float red_s[8];

    for (int i = tid; i < 512; i += 256) {
        mu_s[i] = tok_mu[h * 512 + i];
        float lv = tok_log_var[h * 512 + i];
        iv_s[i] = __expf(-lv);
    }
    if (tid < 8) {
        float ls = 0.f, al = 0.f;
        for (int d = 0; d < 64; ++d) {
            float lv = tok_log_var[(h * 8 + tid) * 64 + d];
            ls += lv;
            al += 0.01f * __expf(-lv) + lv;
        }
        lvsum_s[tid] = ls; alpha_s[tid] = al;
    }
    if (tid == 0) {
        float lp[8]; float mx = -1e30f;
        for (int c = 0; c < 8; ++c) { lp[c] = tok_log_prior[h * 8 + c]; mx = fmaxf(mx, lp[c]); }
        float se = 0.f;
        for (int c = 0; c < 8; ++c) se += __expf(lp[c] - mx);
        float lse = mx + __logf(se);
        for (int c = 0; c < 8; ++c) { logp_s[c] = lp[c] - lse; prior_s[c] = __expf(lp[c] - lse); }
    }
    __syncthreads();

    const int l = blockIdx.x * 256 + tid;
    const float4* xp = (const float4*)(src + ((size_t)(b * NL + l)) * ND + h * NDK);
    float4 xr[16];
#pragma unroll
    for (int i = 0; i < 16; ++i) xr[i] = xp[i];

    float ms[8];
#pragma unroll
    for (int c = 0; c < 8; ++c) {
        const float4* mc = (const float4*)(mu_s + c * 64);
        const float4* ic = (const float4*)(iv_s + c * 64);
        float s = 0.f;
#pragma unroll
        for (int i = 0; i < 16; ++i) {
            float4 m4 = mc[i], v4 = ic[i], x4 = xr[i];
            float dx = x4.x - m4.x; s = fmaf(dx * dx, v4.x, s);
            float dy = x4.y - m4.y; s = fmaf(dy * dy, v4.y, s);
            float dz = x4.z - m4.z; s = fmaf(dz * dz, v4.z, s);
            float dw = x4.w - m4.w; s = fmaf(dw * dw, v4.w, s);
        }
        ms[c] = s;
    }

    float lpdf[8]; float mx = -1e30f;
#pragma unroll
    for (int c = 0; c < 8; ++c) {
        lpdf[c] = -0.5f * (ms[c] + lvsum_s[c]) + logp_s[c];
        mx = fmaxf(mx, lpdf[c]);
    }
    float e[8]; float se = 0.f;
#pragma unroll
    for (int c = 0; c < 8; ++c) { e[c] = __expf(lpdf[c] - mx); se += e[c]; }
    float lse = __logf(se);
    float inv = 1.f / se;
    float p[8]; float kl1 = 0.f, kl2 = 0.f, sqq = 0.f;
#pragma unroll
    for (int c = 0; c < 8; ++c) {
        p[c] = e[c] * inv;
        float logprob = lpdf[c] - mx - lse;
        kl1 += prior_s[c] * (logp_s[c] - logprob);
        kl2 += p[c] * (ms[c] + alpha_s[c]);
        sqq = fmaf(p[c], p[c], sqq);
    }

    float* po = probs_out + ((size_t)((b * NH + h) * NL + l)) * NC;
    ((float4*)po)[0] = make_float4(p[0], p[1], p[2], p[3]);
    ((float4*)po)[1] = make_float4(p[4], p[5], p[6], p[7]);
#pragma unroll
    for (int c = 0; c < 8; ++c) Pl[tid * 9 + c] = p[c];

    float dterm = 1.25f * (sqq - 1.f) * (sqq - 1.f) - 0.75f * sqq * sqq;
    float klv = kl1 + 0.5f * kl2;
    __syncthreads();

    {
        int qt = tid >> 6, pos = tid & 63, c1 = pos >> 3, c2 = pos & 7;
        float g = 0.f;
        for (int i = 0; i < 64; ++i) {
            int ll = qt * 64 + i;
            g = fmaf(Pl[ll * 9 + c1], Pl[ll * 9 + c2], g);
        }
        Gpart[qt][pos] = g;
    }

#pragma unroll
    for (int o = 32; o > 0; o >>= 1) {
        klv   += __shfl_down(klv, o);
        dterm += __shfl_down(dterm, o);
    }
    if ((tid & 63) == 0) { red_s[tid >> 6] = klv; red_s[4 + (tid >> 6)] = dterm; }
    __syncthreads();
    if (tid == 0) {
        atomicAdd(acc_kl + b,  red_s[0] + red_s[1] + red_s[2] + red_s[3]);
        atomicAdd(acc_div + b, red_s[4] + red_s[5] + red_s[6] + red_s[7]);
    }
    if (tid < 64) {
        float g = Gpart[0][tid] + Gpart[1][tid] + Gpart[2][tid] + Gpart[3][tid];
        atomicAdd(Gacc + ((size_t)((side * NB + b) * NH + h)) * 64 + tid, g);
    }
}

// ---------------------------------------------------------------------------
// bf16 MFMA GEMM: out = (A @ W^T + bias) * scale.
// ABF: A is bf16 (u16) instead of fp32.  OBF: write bf16 output.
// 128x128 tile, BK=32, 4 waves (2x2), 4x4 MFMA tiles per wave.
// ---------------------------------------------------------------------------
struct GemmArgs { const void* A; const float* W; const float* bias; void* out; float scale; };

template<int ABF, int OBF>
__global__ __launch_bounds__(256) void gemm_bt_t(GemmArgs g0, GemmArgs g1, GemmArgs g2)
{
    GemmArgs g = (blockIdx.z == 0) ? g0 : ((blockIdx.z == 1) ? g1 : g2);
    const int tid = threadIdx.x;
    const int n0 = blockIdx.x * 128, m0 = blockIdx.y * 128;

    __shared__ alignas(16) unsigned short As[128 * 40];
    __shared__ alignas(16) unsigned short Ws[128 * 40];

    const int kc = tid & 7;
    const int r0 = tid >> 3;
    const int wave = tid >> 6, lane = tid & 63;
    const int wm = wave >> 1, wn = wave & 1;
    const int r16 = lane & 15, quad = lane >> 4;

    f32x4v acc[4][4];
#pragma unroll
    for (int mi = 0; mi < 4; ++mi)
#pragma unroll
        for (int ni = 0; ni < 4; ++ni)
            acc[mi][ni] = (f32x4v){0.f, 0.f, 0.f, 0.f};

    for (int k0 = 0; k0 < 512; k0 += 32) {
#pragma unroll
        for (int rr = 0; rr < 4; ++rr) {
            const int r = r0 + rr * 32;
            if (ABF) {
                u16x4 ap = *(const u16x4*)((const unsigned short*)g.A + (size_t)(m0 + r) * 512 + k0 + kc * 4);
                *(u16x4*)(As + r * 40 + kc * 4) = ap;
            } else {
                const float4 av = *(const float4*)((const float*)g.A + (size_t)(m0 + r) * 512 + k0 + kc * 4);
                u16x4 ap = { bf16u(av.x), bf16u(av.y), bf16u(av.z), bf16u(av.w) };
                *(u16x4*)(As + r * 40 + kc * 4) = ap;
            }
            const float4 wv = *(const float4*)(g.W + (size_t)(n0 + r) * 512 + k0 + kc * 4);
            u16x4 wp = { bf16u(wv.x), bf16u(wv.y), bf16u(wv.z), bf16u(wv.w) };
            *(u16x4*)(Ws + r * 40 + kc * 4) = wp;
        }
        __syncthreads();

        bf16x8 af[4], bfr[4];
#pragma unroll
        for (int mi = 0; mi < 4; ++mi)
            af[mi] = *(const bf16x8*)(As + (wm * 64 + mi * 16 + r16) * 40 + quad * 8);
#pragma unroll
        for (int ni = 0; ni < 4; ++ni)
            bfr[ni] = *(const bf16x8*)(Ws + (wn * 64 + ni * 16 + r16) * 40 + quad * 8);
#pragma unroll
        for (int mi = 0; mi < 4; ++mi)
#pragma unroll
            for (int ni = 0; ni < 4; ++ni)
                acc[mi][ni] = __builtin_amdgcn_mfma_f32_16x16x32_bf16(af[mi], bfr[ni], acc[mi][ni], 0, 0, 0);
        __syncthreads();
    }

#pragma unroll
    for (int ni = 0; ni < 4; ++ni) {
        const int col = n0 + wn * 64 + ni * 16 + r16;
        const float bv = g.bias[col];
#pragma unroll
        for (int mi = 0; mi < 4; ++mi) {
#pragma unroll
            for (int i = 0; i < 4; ++i) {
                const int row = m0 + wm * 64 + mi * 16 + quad * 4 + i;
                const float v = (acc[mi][ni][i] + bv) * g.scale;
                if (OBF) ((unsigned short*)g.out)[(size_t)row * 512 + col] = bf16u(v);
                else     ((float*)g.out)[(size_t)row * 512 + col] = v;
            }
        }
    }
}

// ---------------------------------------------------------------------------
// V transpose: vp16 [B,L,512] bf16 -> vt16 [B][H][64 dims][1024 keys] bf16.
// One 64-key tile per block; done ONCE per (b,h) instead of 16x inside attn.
// grid: (16, 8, 4)  block: 256
// ---------------------------------------------------------------------------
__global__ __launch_bounds__(256) void vtrans_kernel(
    const unsigned short* __restrict__ vp16, unsigned short* __restrict__ vt16)
{
    const int tid = threadIdx.x;
    const int b = blockIdx.z, h = blockIdx.y, key0 = blockIdx.x * 64;

    __shared__ unsigned short Ts[64 * 70];

    {
        const int key = tid & 63, dc = tid >> 6;
        const unsigned short* vr = vp16 + ((size_t)(b * NL + key0 + key)) * ND + h * NDK + dc * 16;
        u16x8 a0 = *(const u16x8*)vr;
        u16x8 a1 = *(const u16x8*)(vr + 8);
        *(u16x8*)(Ts + key * 70 + dc * 16) = a0;
        *(u16x8*)(Ts + key * 70 + dc * 16 + 8) = a1;
    }
    __syncthreads();
    {
        const int dim = tid >> 2, kc = tid & 3;
        unsigned short tmp[16];
#pragma unroll
        for (int j = 0; j < 16; ++j) tmp[j] = Ts[(kc * 16 + j) * 70 + dim];
        unsigned short* orow = vt16 + ((size_t)((b * NH + h) * 64 + dim)) * NL + key0 + kc * 16;
        *(u16x8*)orow = *(u16x8*)tmp;
        *(u16x8*)(orow + 8) = *(u16x8*)(tmp + 8);
    }
}

// ---------------------------------------------------------------------------
// MFMA flash attention v2 (bf16 global q/k/vt, pk/pm hoisted into LDS).
// Block = 64 q-rows of one (b,h); 4 waves each own a 16-row strip; 16 K-tiles.
// grid: (16, 8, 4)  block: 256.  LDS ~63KB -> 2 blocks/CU (= grid cap).
// ---------------------------------------------------------------------------
#define APAD 72

__global__ __launch_bounds__(256) void attn_mfma2_kernel(
    const unsigned short* __restrict__ qp16, const unsigned short* __restrict__ kp16,
    const unsigned short* __restrict__ vt16,
    const float* __restrict__ probs_q, const float* __restrict__ probs_k,
    const float* __restrict__ padding_mask, unsigned short* __restrict__ ao16)
{
    const int tid = threadIdx.x, lane = tid & 63, w = tid >> 6;
    const int r16 = lane & 15, quad = lane >> 4;
    const int b = blockIdx.z, h = blockIdx.y;
    const int qbase = blockIdx.x * 64;

    __shared__ alignas(16) unsigned short Ks[64 * APAD];
    __shared__ alignas(16) unsigned short Vt[64 * APAD];     // [dim][key]
    __shared__ alignas(16) unsigned short Ps[4][16 * APAD];
    __shared__ float pk_all[8 * 1025];                       // [c][key], whole seq
    __shared__ alignas(16) float pm_s[1024];

    // ---- one-time preload: pk (transposed), pm ----
#pragma unroll
    for (int j = 0; j < 8; ++j) {
        const int lin4 = j * 256 + tid;          // 2048 float4 total
        const int key = lin4 >> 1, half = lin4 & 1;
        float4 p = *(const float4*)(probs_k + ((size_t)((b * NH + h) * NL + key)) * NC + half * 4);
        pk_all[(half * 4 + 0) * 1025 + key] = p.x;
        pk_all[(half * 4 + 1) * 1025 + key] = p.y;
        pk_all[(half * 4 + 2) * 1025 + key] = p.z;
        pk_all[(half * 4 + 3) * 1025 + key] = p.w;
    }
    *(float4*)(pm_s + tid * 4) = *(const float4*)(padding_mask + b * NL + tid * 4);

    // ---- per-lane Q A-frags (bf16 global, single 16B loads) ----
    bf16x8 qa[2];
    {
        const unsigned short* qrow = qp16 + ((size_t)(b * NL + qbase + w * 16 + r16)) * ND + h * NDK;
        qa[0] = *(const bf16x8*)(qrow + quad * 8);
        qa[1] = *(const bf16x8*)(qrow + 32 + quad * 8);
    }
    // probs_q rows for this lane's C-layout rows (quad*4+i), fp32.
    float pq[4][8];
#pragma unroll
    for (int i = 0; i < 4; ++i) {
        const float* pr = probs_q + ((size_t)((b * NH + h) * NL + qbase + w * 16 + quad * 4 + i)) * NC;
        float4 a = ((const float4*)pr)[0], c = ((const float4*)pr)[1];
        pq[i][0] = a.x; pq[i][1] = a.y; pq[i][2] = a.z; pq[i][3] = a.w;
        pq[i][4] = c.x; pq[i][5] = c.y; pq[i][6] = c.z; pq[i][7] = c.w;
    }

    f32x4v oacc[4];
#pragma unroll
    for (int n = 0; n < 4; ++n) oacc[n] = (f32x4v){0.f, 0.f, 0.f, 0.f};
    float m_i[4] = {-1e30f, -1e30f, -1e30f, -1e30f};
    float l_i[4] = {0.f, 0.f, 0.f, 0.f};

    for (int kt = 0; kt < 16; ++kt) {
        const int key0 = kt * 64;
        __syncthreads();   // prev-tile LDS reads done (also fences the preload once)

        // ---- stage K tile [key][dim] and Vt tile [dim][key], u16x8 -> b128 ----
#pragma unroll
        for (int i = 0; i < 2; ++i) {
            const int c = i * 256 + tid;           // 512 chunks of 8 u16 each
            const int row = c >> 3, c8 = c & 7;
            u16x8 kv = *(const u16x8*)(kp16 + ((size_t)(b * NL + key0 + row)) * ND + h * NDK + c8 * 8);
            *(u16x8*)(Ks + row * APAD + c8 * 8) = kv;
            u16x8 vv = *(const u16x8*)(vt16 + ((size_t)((b * NH + h) * 64 + row)) * NL + key0 + c8 * 8);
            *(u16x8*)(Vt + row * APAD + c8 * 8) = vv;
        }
        __syncthreads();

        // ---- S = Q K^T ----
        f32x4v sacc[4];
#pragma unroll
        for (int t = 0; t < 4; ++t) {
            sacc[t] = (f32x4v){0.f, 0.f, 0.f, 0.f};
            bf16x8 kb0 = *(const bf16x8*)(Ks + (t * 16 + r16) * APAD + quad * 8);
            bf16x8 kb1 = *(const bf16x8*)(Ks + (t * 16 + r16) * APAD + 32 + quad * 8);
            sacc[t] = __builtin_amdgcn_mfma_f32_16x16x32_bf16(qa[0], kb0, sacc[t], 0, 0, 0);
            sacc[t] = __builtin_amdgcn_mfma_f32_16x16x32_bf16(qa[1], kb1, sacc[t], 0, 0, 0);
        }

        // ---- sim (fp32 VALU; needs full precision: enters exponent x10000) ----
        float sc[4][4], wgt[4][4];
#pragma unroll
        for (int t = 0; t < 4; ++t) {
            const int keyg = key0 + t * 16 + r16;
            float pkc[8];
#pragma unroll
            for (int c = 0; c < 8; ++c) pkc[c] = pk_all[c * 1025 + keyg];
            const float pmv = pm_s[keyg];
#pragma unroll
            for (int i = 0; i < 4; ++i) {
                float sim = 0.f;
#pragma unroll
                for (int c = 0; c < 8; ++c) sim = fmaf(pq[i][c], pkc[c], sim);
                float cm = 1.f - sim + pmv;
                cm = fminf(fmaxf(cm, 0.f), 1.f);
                sc[t][i] = sacc[t][i] - 10000.f * cm;
                wgt[t][i] = 1.f - cm;
            }
        }

        // ---- online softmax (row stats over 16-lane quad group) ----
        float mx[4];
#pragma unroll
        for (int i = 0; i < 4; ++i)
            mx[i] = fmaxf(fmaxf(sc[0][i], sc[1][i]), fmaxf(sc[2][i], sc[3][i]));
#pragma unroll
        for (int o = 1; o < 16; o <<= 1) {
#pragma unroll
            for (int i = 0; i < 4; ++i) mx[i] = fmaxf(mx[i], __shfl_xor(mx[i], o));
        }
        float rr[4];
#pragma unroll
        for (int i = 0; i < 4; ++i) {
            const float mnew = fmaxf(m_i[i], mx[i]);
            rr[i] = __expf(m_i[i] - mnew);
            m_i[i] = mnew;
            l_i[i] *= rr[i];
        }
#pragma unroll
        for (int n = 0; n < 4; ++n) {
            oacc[n][0] *= rr[0]; oacc[n][1] *= rr[1];
            oacc[n][2] *= rr[2]; oacc[n][3] *= rr[3];
        }
        float lad[4] = {0.f, 0.f, 0.f, 0.f};
#pragma unroll
        for (int t = 0; t < 4; ++t) {
#pragma unroll
            for (int i = 0; i < 4; ++i) {
                const float p = __expf(sc[t][i] - m_i[i]);
                lad[i] += p;
                Ps[w][(quad * 4 + i) * APAD + t * 16 + r16] = bf16u(p * wgt[t][i]);
            }
        }
#pragma unroll
        for (int o = 1; o < 16; o <<= 1) {
#pragma unroll
            for (int i = 0; i < 4; ++i) lad[i] += __shfl_xor(lad[i], o);
        }
#pragma unroll
        for (int i = 0; i < 4; ++i) l_i[i] += lad[i];

        // ---- O += P' V ----
        bf16x8 pa0 = *(const bf16x8*)(Ps[w] + r16 * APAD + quad * 8);
        bf16x8 pa1 = *(const bf16x8*)(Ps[w] + r16 * APAD + 32 + quad * 8);
#pragma unroll
        for (int n = 0; n < 4; ++n) {
            bf16x8 vb0 = *(const bf16x8*)(Vt + (n * 16 + r16) * APAD + quad * 8);
            bf16x8 vb1 = *(const bf16x8*)(Vt + (n * 16 + r16) * APAD + 32 + quad * 8);
            oacc[n] = __builtin_amdgcn_mfma_f32_16x16x32_bf16(pa0, vb0, oacc[n], 0, 0, 0);
            oacc[n] = __builtin_amdgcn_mfma_f32_16x16x32_bf16(pa1, vb1, oacc[n], 0, 0, 0);
        }
    }

    // ---- epilogue: O / l, bf16 out (final GEMM would round to bf16 anyway) ----
#pragma unroll
    for (int i = 0; i < 4; ++i) {
        const float inv = 1.f / l_i[i];
        const int q = qbase + w * 16 + quad * 4 + i;
        unsigned short* orow = ao16 + ((size_t)(b * NL + q)) * ND + h * NDK;
#pragma unroll
        for (int n = 0; n < 4; ++n) orow[n * 16 + r16] = bf16u(oacc[n][i] * inv);
    }
}

// ---------------------------------------------------------------------------
// Finalize scalars: kl_loss[b], div_loss[b]
// ---------------------------------------------------------------------------
__global__ void finalize_kernel(const float* __restrict__ acc_kl, const float* __restrict__ acc_div,
                                const float* __restrict__ Gacc, float* __restrict__ out_tail)
{
    const int b = threadIdx.x;
    if (b < NB) {
        float gsum = 0.f;
        for (int s = 0; s < 2; ++s)
            for (int i = 0; i < 512; ++i) {
                float g = Gacc[s * 2048 + b * 512 + i];
                gsum = fmaf(g, g, gsum);
            }
        out_tail[b]      = acc_kl[b] * (1.0f / 8192.0f) + 2.0f * KL3_CONST;
        out_tail[4 + b]  = (acc_div[b] + 0.75f * gsum) * (1.0f / 8388608.0f);
    }
}

// ---------------------------------------------------------------------------
extern "C" void kernel_launch(void* const* d_in, const int* in_sizes, int n_in,
                              void* d_out, int out_size, void* d_ws, size_t ws_size,
                              hipStream_t stream)
{
    const float* query        = (const float*)d_in[0];
    const float* key          = (const float*)d_in[1];
    const float* value        = (const float*)d_in[2];
    const float* padding_mask = (const float*)d_in[3];
    const float* Wq = (const float*)d_in[4];
    const float* bq = (const float*)d_in[5];
    const float* Wk = (const float*)d_in[6];
    const float* bk = (const float*)d_in[7];
    const float* Wv = (const float*)d_in[8];
    const float* bv = (const float*)d_in[9];
    const float* Wo = (const float*)d_in[10];
    const float* bo = (const float*)d_in[11];
    const float* tok_mu        = (const float*)d_in[12];
    const float* tok_log_var   = (const float*)d_in[13];
    const float* tok_log_prior = (const float*)d_in[14];

    float* ws = (float*)d_ws;
    const size_t NMAT = (size_t)NB * NL * ND;        // 2097152 elements
    const size_t NH16 = NMAT / 2;                    // bf16 buffer size in float units
    unsigned short* qp16 = (unsigned short*)ws;
    unsigned short* kp16 = (unsigned short*)(ws + NH16);
    unsigned short* vp16 = (unsigned short*)(ws + 2 * NH16);
    unsigned short* vt16 = (unsigned short*)(ws + 3 * NH16);
    unsigned short* ao16 = (unsigned short*)(ws + 4 * NH16);
    float* probs_q = ws + 5 * NH16;                  // 262144 floats each
    float* probs_k = probs_q + (size_t)NB * NH * NL * NC;
    float* acc_kl  = probs_k + (size_t)NB * NH * NL * NC;
    float* acc_div = acc_kl + 4;
    float* Gacc    = acc_div + 4;                    // 2*B*H*64 = 4096

    hipMemsetAsync(acc_kl, 0, (4 + 4 + 4096) * sizeof(float), stream);

    cluster_kernel<<<dim3(NL / 256, NB * NH, 2), 256, 0, stream>>>(
        query, key, tok_mu, tok_log_var, tok_log_prior,
        probs_q, probs_k, acc_kl, acc_div, Gacc);

    GemmArgs gq{query, Wq, bq, qp16, 0.125f};   // /sqrt(Dk) folded in
    GemmArgs gk{key,   Wk, bk, kp16, 1.f};
    GemmArgs gv{value, Wv, bv, vp16, 1.f};
    gemm_bt_t<0, 1><<<dim3(4, 32, 3), 256, 0, stream>>>(gq, gk, gv);

    vtrans_kernel<<<dim3(16, NH, NB), 256, 0, stream>>>(vp16, vt16);

    attn_mfma2_kernel<<<dim3(16, NH, NB), 256, 0, stream>>>(
        qp16, kp16, vt16, probs_q, probs_k, padding_mask, ao16);

    GemmArgs go{ao16, Wo, bo, d_out, 1.f};
    gemm_bt_t<1, 0><<<dim3(4, 32, 1), 256, 0, stream>>>(go, go, go);

    finalize_kernel<<<1, 64, 0, stream>>>(acc_kl, acc_div, Gacc, (float*)d_out + NMAT);
}

// Round 5
// 217.667 us; speedup vs baseline: 5.8617x; 1.0262x over previous
//
#include <hip/hip_runtime.h>
#include <hip/hip_bf16.h>
#include <math.h>

// Problem constants: B=4, L=1024, D=512, H=8, C=8, Dk=64
#define NB 4
#define NL 1024
#define ND 512
#define NH 8
#define NC 8
#define NDK 64

static constexpr float KL3_CONST = 115.36544595161891f; // -0.5*(1+ln0.01)*64, per clustering call

typedef __bf16 bf16x8 __attribute__((ext_vector_type(8)));
typedef float  f32x4v __attribute__((ext_vector_type(4)));
typedef unsigned short u16x4 __attribute__((ext_vector_type(4)));
typedef unsigned short u16x8 __attribute__((ext_vector_type(8)));

__device__ __forceinline__ unsigned short bf16u(float f) {
    return __builtin_bit_cast(unsigned short, (__bf16)f);
}

// ---------------------------------------------------------------------------
// Weight conversion: Wq,Wk,Wv,Wo (each 512x512 fp32) -> concatenated bf16.
// grid: 1024 x 256  (262144 float4 chunks)
// ---------------------------------------------------------------------------
__global__ __launch_bounds__(256) void cvt_w_kernel(
    const float* __restrict__ Wq, const float* __restrict__ Wk,
    const float* __restrict__ Wv, const float* __restrict__ Wo,
    unsigned short* __restrict__ W16)
{
    const int idx4 = blockIdx.x * 256 + threadIdx.x;   // 0..262143
    const int sel = idx4 >> 16;
    const float* src = (sel == 0) ? Wq : (sel == 1) ? Wk : (sel == 2) ? Wv : Wo;
    float4 v = ((const float4*)src)[idx4 & 65535];
    u16x4 o = { bf16u(v.x), bf16u(v.y), bf16u(v.z), bf16u(v.w) };
    *(u16x4*)(W16 + (size_t)idx4 * 4) = o;
}

// ---------------------------------------------------------------------------
// Clustering: probs, kl partials, div diag partials, Gram G = P^T P, and
// (free, data already in registers) bf16 copies of query/key for the GEMMs.
// grid: (L/256, B*H, 2)  block: 256
// ---------------------------------------------------------------------------
__global__ __launch_bounds__(256) void cluster_kernel(
    const float* __restrict__ query, const float* __restrict__ key,
    const float* __restrict__ tok_mu, const float* __restrict__ tok_log_var,
    const float* __restrict__ tok_log_prior,
    float* __restrict__ probs_q, float* __restrict__ probs_k,
    unsigned short* __restrict__ q16i, unsigned short* __restrict__ k16i,
    float* __restrict__ acc_kl, float* __restrict__ acc_div,
    float* __restrict__ Gacc)
{
    const int tid  = threadIdx.x;
    const int bh   = blockIdx.y;
    const int b    = bh >> 3, h = bh & 7;
    const int side = blockIdx.z;
    const float* src = side ? key : query;
    float* probs_out = side ? probs_k : probs_q;
    unsigned short* x16 = side ? k16i : q16i;

    __shared__ alignas(16) float mu_s[512];
    __shared__ alignas(16) float iv_s[512];
    __shared__ float lvsum_s[8], alpha_s[8], logp_s[8], prior_s[8];
    __shared__ float Pl[256 * 9];
    __shared__ float Gpart[4][64];
    __shared__ float red_s[8];

    for (int i = tid; i < 512; i += 256) {
        mu_s[i] = tok_mu[h * 512 + i];
        float lv = tok_log_var[h * 512 + i];
        iv_s[i] = __expf(-lv);
    }
    if (tid < 8) {
        float ls = 0.f, al = 0.f;
        for (int d = 0; d < 64; ++d) {
            float lv = tok_log_var[(h * 8 + tid) * 64 + d];
            ls += lv;
            al += 0.01f * __expf(-lv) + lv;
        }
        lvsum_s[tid] = ls; alpha_s[tid] = al;
    }
    if (tid == 0) {
        float lp[8]; float mx = -1e30f;
        for (int c = 0; c < 8; ++c) { lp[c] = tok_log_prior[h * 8 + c]; mx = fmaxf(mx, lp[c]); }
        float se = 0.f;
        for (int c = 0; c < 8; ++c) se += __expf(lp[c] - mx);
        float lse = mx + __logf(se);
        for (int c = 0; c < 8; ++c) { logp_s[c] = lp[c] - lse; prior_s[c] = __expf(lp[c] - lse); }
    }
    __syncthreads();

    const int l = blockIdx.x * 256 + tid;
    const float4* xp = (const float4*)(src + ((size_t)(b * NL + l)) * ND + h * NDK);
    float4 xr[16];
#pragma unroll
    for (int i = 0; i < 16; ++i) xr[i] = xp[i];

    // free bf16 emit of this thread's h-slice (row l, dims h*64..h*64+63)
    {
        unsigned short* dst = x16 + ((size_t)(b * NL + l)) * ND + h * NDK;
#pragma unroll
        for (int i2 = 0; i2 < 8; ++i2) {
            float4 a = xr[2 * i2], c2 = xr[2 * i2 + 1];
            u16x8 o = { bf16u(a.x), bf16u(a.y), bf16u(a.z), bf16u(a.w),
                        bf16u(c2.x), bf16u(c2.y), bf16u(c2.z), bf16u(c2.w) };
            *(u16x8*)(dst + i2 * 8) = o;
        }
    }

    float ms[8];
#pragma unroll
    for (int c = 0; c < 8; ++c) {
        const float4* mc = (const float4*)(mu_s + c * 64);
        const float4* ic = (const float4*)(iv_s + c * 64);
        float s = 0.f;
#pragma unroll
        for (int i = 0; i < 16; ++i) {
            float4 m4 = mc[i], v4 = ic[i], x4 = xr[i];
            float dx = x4.x - m4.x; s = fmaf(dx * dx, v4.x, s);
            float dy = x4.y - m4.y; s = fmaf(dy * dy, v4.y, s);
            float dz = x4.z - m4.z; s = fmaf(dz * dz, v4.z, s);
            float dw = x4.w - m4.w; s = fmaf(dw * dw, v4.w, s);
        }
        ms[c] = s;
    }

    float lpdf[8]; float mx = -1e30f;
#pragma unroll
    for (int c = 0; c < 8; ++c) {
        lpdf[c] = -0.5f * (ms[c] + lvsum_s[c]) + logp_s[c];
        mx = fmaxf(mx, lpdf[c]);
    }
    float e[8]; float se = 0.f;
#pragma unroll
    for (int c = 0; c < 8; ++c) { e[c] = __expf(lpdf[c] - mx); se += e[c]; }
    float lse = __logf(se);
    float inv = 1.f / se;
    float p[8]; float kl1 = 0.f, kl2 = 0.f, sqq = 0.f;
#pragma unroll
    for (int c = 0; c < 8; ++c) {
        p[c] = e[c] * inv;
        float logprob = lpdf[c] - mx - lse;
        kl1 += prior_s[c] * (logp_s[c] - logprob);
        kl2 += p[c] * (ms[c] + alpha_s[c]);
        sqq = fmaf(p[c], p[c], sqq);
    }

    float* po = probs_out + ((size_t)((b * NH + h) * NL + l)) * NC;
    ((float4*)po)[0] = make_float4(p[0], p[1], p[2], p[3]);
    ((float4*)po)[1] = make_float4(p[4], p[5], p[6], p[7]);
#pragma unroll
    for (int c = 0; c < 8; ++c) Pl[tid * 9 + c] = p[c];

    float dterm = 1.25f * (sqq - 1.f) * (sqq - 1.f) - 0.75f * sqq * sqq;
    float klv = kl1 + 0.5f * kl2;
    __syncthreads();

    {
        int qt = tid >> 6, pos = tid & 63, c1 = pos >> 3, c2 = pos & 7;
        float g = 0.f;
        for (int i = 0; i < 64; ++i) {
            int ll = qt * 64 + i;
            g = fmaf(Pl[ll * 9 + c1], Pl[ll * 9 + c2], g);
        }
        Gpart[qt][pos] = g;
    }

#pragma unroll
    for (int o = 32; o > 0; o >>= 1) {
        klv   += __shfl_down(klv, o);
        dterm += __shfl_down(dterm, o);
    }
    if ((tid & 63) == 0) { red_s[tid >> 6] = klv; red_s[4 + (tid >> 6)] = dterm; }
    __syncthreads();
    if (tid == 0) {
        atomicAdd(acc_kl + b,  red_s[0] + red_s[1] + red_s[2] + red_s[3]);
        atomicAdd(acc_div + b, red_s[4] + red_s[5] + red_s[6] + red_s[7]);
    }
    if (tid < 64) {
        float g = Gpart[0][tid] + Gpart[1][tid] + Gpart[2][tid] + Gpart[3][tid];
        atomicAdd(Gacc + ((size_t)((side * NB + b) * NH + h)) * 64 + tid, g);
    }
}

// ---------------------------------------------------------------------------
// bf16 MFMA GEMM: out[row][col] = (Sum_k A[row][k]*W[col][k] + bias) * scale.
// ABF/WBF: operand already bf16.  OBF: bf16 output.  BROW: bias indexed by
// row (for the transposed-V gemm).  OSTR: output row stride.
// 128x128 tile, BK=32, 4 waves (2x2), 4x4 MFMA tiles per wave.
// ---------------------------------------------------------------------------
struct GemmArgs { const void* A; const void* W; const float* bias; void* out; float scale; };

template<int ABF, int WBF, int OBF, int BROW, int OSTR>
__global__ __launch_bounds__(256) void gemm_bt_t(GemmArgs g0, GemmArgs g1, GemmArgs g2)
{
    GemmArgs g = (blockIdx.z == 0) ? g0 : ((blockIdx.z == 1) ? g1 : g2);
    const int tid = threadIdx.x;
    const int n0 = blockIdx.x * 128, m0 = blockIdx.y * 128;

    __shared__ alignas(16) unsigned short As[128 * 40];
    __shared__ alignas(16) unsigned short Ws[128 * 40];

    const int kc = tid & 7;
    const int r0 = tid >> 3;
    const int wave = tid >> 6, lane = tid & 63;
    const int wm = wave >> 1, wn = wave & 1;
    const int r16 = lane & 15, quad = lane >> 4;

    f32x4v acc[4][4];
#pragma unroll
    for (int mi = 0; mi < 4; ++mi)
#pragma unroll
        for (int ni = 0; ni < 4; ++ni)
            acc[mi][ni] = (f32x4v){0.f, 0.f, 0.f, 0.f};

    for (int k0 = 0; k0 < 512; k0 += 32) {
#pragma unroll
        for (int rr = 0; rr < 4; ++rr) {
            const int r = r0 + rr * 32;
            if (ABF) {
                u16x4 ap = *(const u16x4*)((const unsigned short*)g.A + (size_t)(m0 + r) * 512 + k0 + kc * 4);
                *(u16x4*)(As + r * 40 + kc * 4) = ap;
            } else {
                const float4 av = *(const float4*)((const float*)g.A + (size_t)(m0 + r) * 512 + k0 + kc * 4);
                u16x4 ap = { bf16u(av.x), bf16u(av.y), bf16u(av.z), bf16u(av.w) };
                *(u16x4*)(As + r * 40 + kc * 4) = ap;
            }
            if (WBF) {
                u16x4 wp = *(const u16x4*)((const unsigned short*)g.W + (size_t)(n0 + r) * 512 + k0 + kc * 4);
                *(u16x4*)(Ws + r * 40 + kc * 4) = wp;
            } else {
                const float4 wv = *(const float4*)((const float*)g.W + (size_t)(n0 + r) * 512 + k0 + kc * 4);
                u16x4 wp = { bf16u(wv.x), bf16u(wv.y), bf16u(wv.z), bf16u(wv.w) };
                *(u16x4*)(Ws + r * 40 + kc * 4) = wp;
            }
        }
        __syncthreads();

        bf16x8 af[4], bfr[4];
#pragma unroll
        for (int mi = 0; mi < 4; ++mi)
            af[mi] = *(const bf16x8*)(As + (wm * 64 + mi * 16 + r16) * 40 + quad * 8);
#pragma unroll
        for (int ni = 0; ni < 4; ++ni)
            bfr[ni] = *(const bf16x8*)(Ws + (wn * 64 + ni * 16 + r16) * 40 + quad * 8);
#pragma unroll
        for (int mi = 0; mi < 4; ++mi)
#pragma unroll
            for (int ni = 0; ni < 4; ++ni)
                acc[mi][ni] = __builtin_amdgcn_mfma_f32_16x16x32_bf16(af[mi], bfr[ni], acc[mi][ni], 0, 0, 0);
        __syncthreads();
    }

#pragma unroll
    for (int ni = 0; ni < 4; ++ni) {
        const int col = n0 + wn * 64 + ni * 16 + r16;
        const float bcol = BROW ? 0.f : g.bias[col];
#pragma unroll
        for (int mi = 0; mi < 4; ++mi) {
#pragma unroll
            for (int i = 0; i < 4; ++i) {
                const int row = m0 + wm * 64 + mi * 16 + quad * 4 + i;
                const float bv = BROW ? g.bias[row] : bcol;
                const float v = (acc[mi][ni][i] + bv) * g.scale;
                if (OBF) ((unsigned short*)g.out)[(size_t)row * OSTR + col] = bf16u(v);
                else     ((float*)g.out)[(size_t)row * OSTR + col] = v;
            }
        }
    }
}

// ---------------------------------------------------------------------------
// MFMA flash attention v3: 32 q-rows/block, 128 threads (2 waves), each wave
// owns a 16-row strip across ALL keys; 16 K-tiles of 64. pk/pm staged per
// tile (LDS ~25KB -> 4-6 blocks/CU at grid 1024 -> 3x occupancy of v2).
// grid: (32, 8, 4)  block: 128
// ---------------------------------------------------------------------------
#define APAD 72

__global__ __launch_bounds__(128) void attn_mfma3_kernel(
    const unsigned short* __restrict__ qp16, const unsigned short* __restrict__ kp16,
    const unsigned short* __restrict__ vtp16,
    const float* __restrict__ probs_q, const float* __restrict__ probs_k,
    const float* __restrict__ padding_mask, unsigned short* __restrict__ ao16)
{
    const int tid = threadIdx.x, lane = tid & 63, w = tid >> 6;
    const int r16 = lane & 15, quad = lane >> 4;
    const int b = blockIdx.z, h = blockIdx.y;
    const int qbase = blockIdx.x * 32;

    __shared__ alignas(16) unsigned short Ks[64 * APAD];
    __shared__ alignas(16) unsigned short Vt[64 * APAD];   // [dim][key]
    __shared__ alignas(16) unsigned short Ps[2][16 * APAD];
    __shared__ float pk_s[8 * 65];                         // [c][key] per tile
    __shared__ float pm_s[64];

    bf16x8 qa[2];
    {
        const unsigned short* qrow = qp16 + ((size_t)(b * NL + qbase + w * 16 + r16)) * ND + h * NDK;
        qa[0] = *(const bf16x8*)(qrow + quad * 8);
        qa[1] = *(const bf16x8*)(qrow + 32 + quad * 8);
    }
    float pq[4][8];
#pragma unroll
    for (int i = 0; i < 4; ++i) {
        const float* pr = probs_q + ((size_t)((b * NH + h) * NL + qbase + w * 16 + quad * 4 + i)) * NC;
        float4 a = ((const float4*)pr)[0], c = ((const float4*)pr)[1];
        pq[i][0] = a.x; pq[i][1] = a.y; pq[i][2] = a.z; pq[i][3] = a.w;
        pq[i][4] = c.x; pq[i][5] = c.y; pq[i][6] = c.z; pq[i][7] = c.w;
    }

    f32x4v oacc[4];
#pragma unroll
    for (int n = 0; n < 4; ++n) oacc[n] = (f32x4v){0.f, 0.f, 0.f, 0.f};
    float m_i[4] = {-1e30f, -1e30f, -1e30f, -1e30f};
    float l_i[4] = {0.f, 0.f, 0.f, 0.f};

    for (int kt = 0; kt < 16; ++kt) {
        const int key0 = kt * 64;
        __syncthreads();   // all reads of prev tile done

        // ---- stage K [key][dim], Vt [dim][key], pk (transposed), pm ----
#pragma unroll
        for (int i = 0; i < 4; ++i) {
            const int c = i * 128 + tid;          // 512 chunks of 8 u16
            const int row = c >> 3, c8 = c & 7;
            u16x8 kv = *(const u16x8*)(kp16 + ((size_t)(b * NL + key0 + row)) * ND + h * NDK + c8 * 8);
            *(u16x8*)(Ks + row * APAD + c8 * 8) = kv;
            u16x8 vv = *(const u16x8*)(vtp16 + ((size_t)(h * 64 + row)) * (NB * NL) + b * NL + key0 + c8 * 8);
            *(u16x8*)(Vt + row * APAD + c8 * 8) = vv;
        }
        {
            const int key = tid >> 1, half = tid & 1;
            float4 p = *(const float4*)(probs_k + ((size_t)((b * NH + h) * NL + key0 + key)) * NC + half * 4);
            pk_s[(half * 4 + 0) * 65 + key] = p.x;
            pk_s[(half * 4 + 1) * 65 + key] = p.y;
            pk_s[(half * 4 + 2) * 65 + key] = p.z;
            pk_s[(half * 4 + 3) * 65 + key] = p.w;
        }
        if (tid < 64) pm_s[tid] = padding_mask[b * NL + key0 + tid];
        __syncthreads();

        // ---- S = Q K^T ----
        f32x4v sacc[4];
#pragma unroll
        for (int t = 0; t < 4; ++t) {
            sacc[t] = (f32x4v){0.f, 0.f, 0.f, 0.f};
            bf16x8 kb0 = *(const bf16x8*)(Ks + (t * 16 + r16) * APAD + quad * 8);
            bf16x8 kb1 = *(const bf16x8*)(Ks + (t * 16 + r16) * APAD + 32 + quad * 8);
            sacc[t] = __builtin_amdgcn_mfma_f32_16x16x32_bf16(qa[0], kb0, sacc[t], 0, 0, 0);
            sacc[t] = __builtin_amdgcn_mfma_f32_16x16x32_bf16(qa[1], kb1, sacc[t], 0, 0, 0);
        }

        // ---- sim (fp32 VALU: enters exponent x10000, needs full precision) ----
        float sc[4][4], wgt[4][4];
#pragma unroll
        for (int t = 0; t < 4; ++t) {
            const int keyl = t * 16 + r16;
            float pkc[8];
#pragma unroll
            for (int c = 0; c < 8; ++c) pkc[c] = pk_s[c * 65 + keyl];
            const float pmv = pm_s[keyl];
#pragma unroll
            for (int i = 0; i < 4; ++i) {
                float sim = 0.f;
#pragma unroll
                for (int c = 0; c < 8; ++c) sim = fmaf(pq[i][c], pkc[c], sim);
                float cm = 1.f - sim + pmv;
                cm = fminf(fmaxf(cm, 0.f), 1.f);
                sc[t][i] = sacc[t][i] - 10000.f * cm;
                wgt[t][i] = 1.f - cm;
            }
        }

        // ---- online softmax (row stats over the 16-lane quad group) ----
        float mx[4];
#pragma unroll
        for (int i = 0; i < 4; ++i)
            mx[i] = fmaxf(fmaxf(sc[0][i], sc[1][i]), fmaxf(sc[2][i], sc[3][i]));
#pragma unroll
        for (int o = 1; o < 16; o <<= 1) {
#pragma unroll
            for (int i = 0; i < 4; ++i) mx[i] = fmaxf(mx[i], __shfl_xor(mx[i], o));
        }
        float rr[4];
#pragma unroll
        for (int i = 0; i < 4; ++i) {
            const float mnew = fmaxf(m_i[i], mx[i]);
            rr[i] = __expf(m_i[i] - mnew);
            m_i[i] = mnew;
            l_i[i] *= rr[i];
        }
#pragma unroll
        for (int n = 0; n < 4; ++n) {
            oacc[n][0] *= rr[0]; oacc[n][1] *= rr[1];
            oacc[n][2] *= rr[2]; oacc[n][3] *= rr[3];
        }
        float lad[4] = {0.f, 0.f, 0.f, 0.f};
#pragma unroll
        for (int t = 0; t < 4; ++t) {
#pragma unroll
            for (int i = 0; i < 4; ++i) {
                const float p = __expf(sc[t][i] - m_i[i]);
                lad[i] += p;
                Ps[w][(quad * 4 + i) * APAD + t * 16 + r16] = bf16u(p * wgt[t][i]);
            }
        }
#pragma unroll
        for (int o = 1; o < 16; o <<= 1) {
#pragma unroll
            for (int i = 0; i < 4; ++i) lad[i] += __shfl_xor(lad[i], o);
        }
#pragma unroll
        for (int i = 0; i < 4; ++i) l_i[i] += lad[i];

        // ---- O += P' V ----
        bf16x8 pa0 = *(const bf16x8*)(Ps[w] + r16 * APAD + quad * 8);
        bf16x8 pa1 = *(const bf16x8*)(Ps[w] + r16 * APAD + 32 + quad * 8);
#pragma unroll
        for (int n = 0; n < 4; ++n) {
            bf16x8 vb0 = *(const bf16x8*)(Vt + (n * 16 + r16) * APAD + quad * 8);
            bf16x8 vb1 = *(const bf16x8*)(Vt + (n * 16 + r16) * APAD + 32 + quad * 8);
            oacc[n] = __builtin_amdgcn_mfma_f32_16x16x32_bf16(pa0, vb0, oacc[n], 0, 0, 0);
            oacc[n] = __builtin_amdgcn_mfma_f32_16x16x32_bf16(pa1, vb1, oacc[n], 0, 0, 0);
        }
    }

    // ---- epilogue: O / l, bf16 out ----
#pragma unroll
    for (int i = 0; i < 4; ++i) {
        const float inv = 1.f / l_i[i];
        const int q = qbase + w * 16 + quad * 4 + i;
        unsigned short* orow = ao16 + ((size_t)(b * NL + q)) * ND + h * NDK;
#pragma unroll
        for (int n = 0; n < 4; ++n) orow[n * 16 + r16] = bf16u(oacc[n][i] * inv);
    }
}

// ---------------------------------------------------------------------------
// Finalize: kl_loss[b], div_loss[b]. 256 thr = 4 waves, one wave per b.
// ---------------------------------------------------------------------------
__global__ void finalize_kernel(const float* __restrict__ acc_kl, const float* __restrict__ acc_div,
                                const float* __restrict__ Gacc, float* __restrict__ out_tail)
{
    const int tid = threadIdx.x, b = tid >> 6, lane = tid & 63;
    float gsum = 0.f;
#pragma unroll
    for (int s = 0; s < 2; ++s)
#pragma unroll
        for (int j = 0; j < 8; ++j) {
            float g = Gacc[s * 2048 + b * 512 + j * 64 + lane];
            gsum = fmaf(g, g, gsum);
        }
#pragma unroll
    for (int o = 32; o > 0; o >>= 1) gsum += __shfl_down(gsum, o);
    if (lane == 0) {
        out_tail[b]     = acc_kl[b] * (1.0f / 8192.0f) + 2.0f * KL3_CONST;
        out_tail[4 + b] = (acc_div[b] + 0.75f * gsum) * (1.0f / 8388608.0f);
    }
}

// ---------------------------------------------------------------------------
extern "C" void kernel_launch(void* const* d_in, const int* in_sizes, int n_in,
                              void* d_out, int out_size, void* d_ws, size_t ws_size,
                              hipStream_t stream)
{
    const float* query        = (const float*)d_in[0];
    const float* key          = (const float*)d_in[1];
    const float* value        = (const float*)d_in[2];
    const float* padding_mask = (const float*)d_in[3];
    const float* Wq = (const float*)d_in[4];
    const float* bq = (const float*)d_in[5];
    const float* Wk = (const float*)d_in[6];
    const float* bk = (const float*)d_in[7];
    const float* Wv = (const float*)d_in[8];
    const float* bv = (const float*)d_in[9];
    const float* Wo = (const float*)d_in[10];
    const float* bo = (const float*)d_in[11];
    const float* tok_mu        = (const float*)d_in[12];
    const float* tok_log_var   = (const float*)d_in[13];
    const float* tok_log_prior = (const float*)d_in[14];

    float* ws = (float*)d_ws;
    const size_t NMAT = (size_t)NB * NL * ND;        // 2097152 elements
    const size_t NH16 = NMAT / 2;                    // bf16 buffer in float-slots
    // buf0: q16i (dead after QK gemm) -> reused as ao16
    // buf1: k16i (dead after QK gemm) -> reused as vtp16 [512][4096]
    unsigned short* q16i  = (unsigned short*)ws;
    unsigned short* ao16  = q16i;
    unsigned short* k16i  = (unsigned short*)(ws + NH16);
    unsigned short* vtp16 = k16i;
    unsigned short* qp16  = (unsigned short*)(ws + 2 * NH16);
    unsigned short* kp16  = (unsigned short*)(ws + 3 * NH16);
    unsigned short* W16   = (unsigned short*)(ws + 4 * NH16);   // 4 x 512x512 bf16
    unsigned short* Wq16 = W16, *Wk16 = W16 + 262144, *Wv16 = W16 + 524288, *Wo16 = W16 + 786432;
    float* probs_q = ws + 4 * NH16 + 524288;
    float* probs_k = probs_q + (size_t)NB * NH * NL * NC;
    float* acc_kl  = probs_k + (size_t)NB * NH * NL * NC;
    float* acc_div = acc_kl + 4;
    float* Gacc    = acc_div + 4;                    // 2*B*H*64 = 4096

    hipMemsetAsync(acc_kl, 0, (4 + 4 + 4096) * sizeof(float), stream);

    cvt_w_kernel<<<1024, 256, 0, stream>>>(Wq, Wk, Wv, Wo, W16);

    cluster_kernel<<<dim3(NL / 256, NB * NH, 2), 256, 0, stream>>>(
        query, key, tok_mu, tok_log_var, tok_log_prior,
        probs_q, probs_k, q16i, k16i, acc_kl, acc_div, Gacc);

    // Q,K projections (all-bf16): out = (x @ W^T + b) [*1/8 for Q]
    GemmArgs gq{q16i, Wq16, bq, qp16, 0.125f};
    GemmArgs gk{k16i, Wk16, bk, kp16, 1.f};
    gemm_bt_t<1, 1, 1, 0, 512><<<dim3(4, 32, 2), 256, 0, stream>>>(gq, gk, gk);

    // V^T projection: vt[dim][tok] = Wv . value^T + bv[dim]  (bias by row)
    GemmArgs gvt{Wv16, value, bv, vtp16, 1.f};
    gemm_bt_t<1, 0, 1, 1, 4096><<<dim3(32, 4, 1), 256, 0, stream>>>(gvt, gvt, gvt);

    attn_mfma3_kernel<<<dim3(32, NH, NB), 128, 0, stream>>>(
        qp16, kp16, vtp16, probs_q, probs_k, padding_mask, ao16);

    GemmArgs go{ao16, Wo16, bo, d_out, 1.f};
    gemm_bt_t<1, 1, 0, 0, 512><<<dim3(4, 32, 1), 256, 0, stream>>>(go, go, go);

    finalize_kernel<<<1, 256, 0, stream>>>(acc_kl, acc_div, Gacc, (float*)d_out + NMAT);
}